// Round 7
// baseline (327.373 us; speedup 1.0000x reference)
//
#include <hip/hip_runtime.h>

#define XD 128
#define YD 128
#define FD 256
#define BD 2048
#define ND (XD*YD)
#define LRB 2.44140625e-4f      // LR/B = 0.5/2048
#define RAD 14                  // exp(-(15^2)/8) ~ 6e-13: below fp32 output resolution
#define MAXS 512

// ---------------- K-init: seed per-sample argmin words ----------------
__global__ __launch_bounds__(256) void init_kernel(unsigned long long* __restrict__ bmu_best) {
  int i = blockIdx.x * 256 + threadIdx.x;
  if (i < BD) bmu_best[i] = ~0ull;
}

// ---------------- K0: per-row squared norm (used for both w and data) ----------------
__global__ __launch_bounds__(256) void rownorm2_kernel(const float* __restrict__ rows,
                                                       float* __restrict__ out) {
  int n = blockIdx.x * 4 + (threadIdx.x >> 6);
  int lane = threadIdx.x & 63;
  float4 v = *reinterpret_cast<const float4*>(rows + (size_t)n * FD + lane * 4);
  float s = v.x * v.x + v.y * v.y + v.z * v.z + v.w * v.w;
#pragma unroll
  for (int m = 32; m; m >>= 1) s += __shfl_xor(s, m);
  if (lane == 0) out[n] = s;
}

// ---------------- K1: BMU GEMM + argmin (atomicMin per sample) ----------------
// Block: 128 samples x 128 neurons, 256 threads, thread tile 8x8, BK=32.
// Fragment->thread remap for conflict-free LDS reads:
//   samples: g + 16*i (per-wave rows step 1, row stride 36 -> banks {0,4,8,12}: no alias)
//   neurons: c*4+j and 64+c*4+j (2-way alias = free per m136)
// Per f0-block per wave: 2048 FMA instr (4096 cyc) vs ~3300 CU-LDS-cyc -> VALU-bound.
__global__ __launch_bounds__(256) void bmu_kernel(const float* __restrict__ data,
                                                  const float* __restrict__ w,
                                                  const float* __restrict__ wn2,
                                                  const float* __restrict__ dn2,
                                                  unsigned long long* __restrict__ bmu_best) {
  __shared__ float As[128][36];   // [sample][f], pad 36 (144B rows: 16B-aligned, bank-step 4)
  __shared__ float Bs[32][132];   // [f][neuron] transposed, pad 132 (528B rows: 16B-aligned)
  const int tid = threadIdx.x;
  const int b0 = blockIdx.x * 128;
  const int n0 = blockIdx.y * 128;
  const int g = tid >> 4;          // sample group 0..15; samples g + 16*i
  const int c = tid & 15;          // neuron group 0..15; neurons c*4+j, 64+c*4+j

  float acc[8][8] = {};            // [i][j]: j<4 -> n=c*4+j, j>=4 -> n=64+c*4+(j-4)

  for (int f0 = 0; f0 < FD; f0 += 32) {
    __syncthreads();
    // stage A: 128x32 floats (1024 float4, 4/thread), coalesced along f
#pragma unroll
    for (int i = 0; i < 4; i++) {
      int idx = i * 256 + tid;
      int r = idx >> 3, c4 = (idx & 7) * 4;
      float4 v = *reinterpret_cast<const float4*>(data + (size_t)(b0 + r) * FD + f0 + c4);
      *reinterpret_cast<float4*>(&As[r][c4]) = v;
    }
    // stage B: 128x32 floats (1024 float4, 4/thread), transpose-scatter into Bs[f][n]
#pragma unroll
    for (int i = 0; i < 4; i++) {
      int idx = i * 256 + tid;
      int r = idx >> 3, c4 = (idx & 7) * 4;
      float4 v = *reinterpret_cast<const float4*>(w + (size_t)(n0 + r) * FD + f0 + c4);
      Bs[c4 + 0][r] = v.x;
      Bs[c4 + 1][r] = v.y;
      Bs[c4 + 2][r] = v.z;
      Bs[c4 + 3][r] = v.w;
    }
    __syncthreads();

#pragma unroll
    for (int k0 = 0; k0 < 32; k0 += 4) {
      float4 a4[8];
#pragma unroll
      for (int i = 0; i < 8; i++)
        a4[i] = *reinterpret_cast<const float4*>(&As[g + 16 * i][k0]);  // conflict-free bcast
#pragma unroll
      for (int kk = 0; kk < 4; kk++) {
        float4 bl = *reinterpret_cast<const float4*>(&Bs[k0 + kk][c * 4]);       // 2-way: free
        float4 bh = *reinterpret_cast<const float4*>(&Bs[k0 + kk][c * 4 + 64]);  // 2-way: free
#pragma unroll
        for (int i = 0; i < 8; i++) {
          float a = (kk == 0) ? a4[i].x : (kk == 1) ? a4[i].y : (kk == 2) ? a4[i].z : a4[i].w;
          acc[i][0] = fmaf(a, bl.x, acc[i][0]);
          acc[i][1] = fmaf(a, bl.y, acc[i][1]);
          acc[i][2] = fmaf(a, bl.z, acc[i][2]);
          acc[i][3] = fmaf(a, bl.w, acc[i][3]);
          acc[i][4] = fmaf(a, bh.x, acc[i][4]);
          acc[i][5] = fmaf(a, bh.y, acc[i][5]);
          acc[i][6] = fmaf(a, bh.z, acc[i][6]);
          acc[i][7] = fmaf(a, bh.w, acc[i][7]);
        }
      }
    }
  }

  // Epilogue mimics the reference's fp32 path: d2 = (dn2 + wn2) - 2*dot (contraction
  // suppressed via *_rn), dist = sqrt(max(d2,0)); key on dist bits so sqrt-grid ties
  // are broken by lowest index exactly like jnp.argmin.
  float w2[8];
#pragma unroll
  for (int j = 0; j < 8; j++) {
    int nl = (j < 4) ? (c * 4 + j) : (64 + c * 4 + (j - 4));
    w2[j] = wn2[n0 + nl];
  }
  unsigned long long best[8];
#pragma unroll
  for (int i = 0; i < 8; i++) {
    float dn2s = dn2[b0 + g + 16 * i];
    best[i] = ~0ull;
#pragma unroll
    for (int j = 0; j < 8; j++) {
      int nl = (j < 4) ? (c * 4 + j) : (64 + c * 4 + (j - 4));
      float t1 = __fadd_rn(dn2s, w2[j]);
      float d2v = __fsub_rn(t1, __fmul_rn(2.0f, acc[i][j]));
      float dist = sqrtf(fmaxf(d2v, 0.0f));
      unsigned key = __float_as_uint(dist);  // dist >= 0: uint order == float order
      unsigned long long p = ((unsigned long long)key << 32) | (unsigned)(n0 + nl);
      best[i] = (p < best[i]) ? p : best[i];
    }
  }
  // reduce across the 16 neuron-groups (xor of tid low 4 bits stays in-wave, same g)
#pragma unroll
  for (int m = 8; m; m >>= 1) {
#pragma unroll
    for (int i = 0; i < 8; i++) {
      unsigned long long o = __shfl_xor(best[i], m);
      best[i] = (o < best[i]) ? o : best[i];
    }
  }
  if (c == 0) {
#pragma unroll
    for (int i = 0; i < 8; i++)
      atomicMin(&bmu_best[b0 + g + 16 * i], best[i]);  // device-scope, order-independent
  }
}

// ---------------- K3: truncated-window gather update ----------------
// Block = one 8x8 neuron tile, 256 threads (thread t owns feature f=t for all
// 64 neurons). Scans samples in chunks of MAXS, compacts in-window ones into
// LDS with separable exp tables, then rank-1 accumulates. BMU coords decoded
// inline from the packed argmin words.
__global__ __launch_bounds__(256) void update_kernel(const float* __restrict__ data,
                                                     const float* __restrict__ w,
                                                     const unsigned long long* __restrict__ bmu_best,
                                                     float* __restrict__ out) {
  __shared__ float axl[MAXS][8];
  __shared__ float ayl[MAXS][8];
  __shared__ int idxl[MAXS];
  __shared__ int cnt;
  __shared__ float red[64][5];
  __shared__ float nbsum_s[64];

  const int tid = threadIdx.x;
  const int tx0 = (blockIdx.x >> 4) * 8;
  const int ty0 = (blockIdx.x & 15) * 8;

  float acc[64] = {};
  float nbp = 0.f;
  const int myn = tid >> 2, q = tid & 3;
  const int mxi = myn >> 3, myi = myn & 7;

  for (int s0 = 0; s0 < BD; s0 += MAXS) {
    if (tid == 0) cnt = 0;
    __syncthreads();
#pragma unroll
    for (int i = 0; i < MAXS / 256; i++) {
      int s = s0 + i * 256 + tid;
      int bidx = (int)(bmu_best[s] & 0xFFFFFFFFull);
      int bx = bidx >> 7, by = bidx & 127;   // x = idx/Y, y = idx%Y
      if (bx >= tx0 - RAD && bx <= tx0 + 7 + RAD &&
          by >= ty0 - RAD && by <= ty0 + 7 + RAD) {
        int pos = atomicAdd(&cnt, 1);
        idxl[pos] = s;
#pragma unroll
        for (int j = 0; j < 8; j++) {
          float dx = (float)(bx - (tx0 + j));
          float dy = (float)(by - (ty0 + j));
          axl[pos][j] = __expf(-dx * dx * 0.125f);
          ayl[pos][j] = __expf(-dy * dy * 0.125f);
        }
      }
    }
    __syncthreads();
    int cn = cnt;
    for (int s = 0; s < cn; s++) {
      float d = data[(size_t)idxl[s] * FD + tid];   // coalesced, L2-resident
#pragma unroll
      for (int xi = 0; xi < 8; xi++) {
        float t = axl[s][xi] * d;                   // LDS broadcast reads
#pragma unroll
        for (int yi = 0; yi < 8; yi++)
          acc[xi * 8 + yi] = fmaf(t, ayl[s][yi], acc[xi * 8 + yi]);
      }
    }
    // nb_sum partial (4 threads per neuron share the list)
    for (int s = q; s < cn; s += 4) nbp += axl[s][mxi] * ayl[s][myi];
    __syncthreads();  // lists reused next chunk
  }

  red[myn][q] = nbp;
  __syncthreads();
  if (tid < 64) nbsum_s[tid] = red[tid][0] + red[tid][1] + red[tid][2] + red[tid][3];
  __syncthreads();

#pragma unroll
  for (int i = 0; i < 64; i++) {
    int n = (tx0 + (i >> 3)) * YD + (ty0 + (i & 7));
    size_t gi = (size_t)n * FD + tid;
    float wv = w[gi];
    out[gi] = fmaf(LRB, acc[i] - nbsum_s[i] * wv, wv);
  }
}

extern "C" void kernel_launch(void* const* d_in, const int* in_sizes, int n_in,
                              void* d_out, int out_size, void* d_ws, size_t ws_size,
                              hipStream_t stream) {
  const float* data = (const float*)d_in[0];
  const float* w = (const float*)d_in[1];
  float* out = (float*)d_out;

  char* ws = (char*)d_ws;
  float* wn2 = (float*)ws;                                           // 64 KB
  float* dn2 = (float*)(ws + 65536);                                 // 8 KB
  unsigned long long* bmu_best = (unsigned long long*)(ws + 73728);  // 16 KB  (total ~90 KB)

  init_kernel<<<(BD + 255) / 256, 256, 0, stream>>>(bmu_best);
  rownorm2_kernel<<<ND / 4, 256, 0, stream>>>(w, wn2);
  rownorm2_kernel<<<BD / 4, 256, 0, stream>>>(data, dn2);
  bmu_kernel<<<dim3(BD / 128, ND / 128), 256, 0, stream>>>(data, w, wn2, dn2, bmu_best);
  update_kernel<<<256, 256, 0, stream>>>(data, w, bmu_best, out);
}

// Round 8
// 201.550 us; speedup vs baseline: 1.6243x; 1.6243x over previous
//
#include <hip/hip_runtime.h>
#include <hip/hip_fp16.h>

#define XD 128
#define YD 128
#define FD 256
#define BD 2048
#define ND (XD*YD)
#define LRB 2.44140625e-4f      // LR/B = 0.5/2048
#define RAD 14                  // exp(-(15^2)/8) ~ 6e-13: below fp32 output resolution
#define MAXS 512

typedef _Float16 f16x8 __attribute__((ext_vector_type(8)));
typedef _Float16 f16x4 __attribute__((ext_vector_type(4)));
typedef float    f32x4 __attribute__((ext_vector_type(4)));

#define GLOAD_LDS16(g, l) \
  __builtin_amdgcn_global_load_lds((const __attribute__((address_space(1))) void*)(g), \
                                   (__attribute__((address_space(3))) void*)(l), 16, 0, 0)

// ---------------- K-init: seed per-sample argmin words ----------------
__global__ __launch_bounds__(256) void init_kernel(unsigned long long* __restrict__ bmu_best) {
  int i = blockIdx.x * 256 + threadIdx.x;
  if (i < BD) bmu_best[i] = ~0ull;
}

// ---------------- K0: per-row squared norm (w and data) ----------------
__global__ __launch_bounds__(256) void rownorm2_kernel(const float* __restrict__ rows,
                                                       float* __restrict__ out) {
  int n = blockIdx.x * 4 + (threadIdx.x >> 6);
  int lane = threadIdx.x & 63;
  float4 v = *reinterpret_cast<const float4*>(rows + (size_t)n * FD + lane * 4);
  float s = v.x * v.x + v.y * v.y + v.z * v.z + v.w * v.w;
#pragma unroll
  for (int m = 32; m; m >>= 1) s += __shfl_xor(s, m);
  if (lane == 0) out[n] = s;
}

// ---------------- K-split: fp32 -> 2-limb fp16 (lo pre-scaled by 2^11) ----------------
__global__ __launch_bounds__(256) void split_kernel(const float* __restrict__ src,
                                                    _Float16* __restrict__ hi,
                                                    _Float16* __restrict__ lo, int n4) {
  int i = blockIdx.x * 256 + threadIdx.x;
  if (i >= n4) return;
  float4 v = reinterpret_cast<const float4*>(src)[i];
  f16x4 h, l;
  h[0] = (_Float16)v.x; l[0] = (_Float16)((v.x - (float)h[0]) * 2048.0f);
  h[1] = (_Float16)v.y; l[1] = (_Float16)((v.y - (float)h[1]) * 2048.0f);
  h[2] = (_Float16)v.z; l[2] = (_Float16)((v.z - (float)h[2]) * 2048.0f);
  h[3] = (_Float16)v.w; l[3] = (_Float16)((v.w - (float)h[3]) * 2048.0f);
  reinterpret_cast<f16x4*>(hi)[i] = h;
  reinterpret_cast<f16x4*>(lo)[i] = l;
}

// Fragment read: mfma_f32_16x16x32_f16 A/B operand for lane (row = lane&15,
// k = (lane>>4)*4 + (j&3) + 16*(j>>2)) from a [rows][32] f16 LDS tile stored
// with 64B rows and bank-swizzle  phys = logical ^ (((row>>1)&3)<<4)
// (16B-block-granular -> composable with linear global_load_lds dest; frag
// ds_read_b64s then spread 2-way/bank = free, per m136).
__device__ __forceinline__ f16x8 readfrag(const char* base, int r, int g) {
  int off = (r * 64 + 8 * g) ^ (((r >> 1) & 3) << 4);
  f16x4 a = *reinterpret_cast<const f16x4*>(base + off);
  f16x4 b = *reinterpret_cast<const f16x4*>(base + (off ^ 32));   // k+16 half
  return __builtin_shufflevector(a, b, 0, 1, 2, 3, 4, 5, 6, 7);
}

// ---------------- K1 (MFMA): split-fp16 BMU GEMM + argmin ----------------
// Block 128 samples x 128 neurons, 4 waves, each wave a 64x64 quadrant
// (4x4 grid of 16x16x32 MFMA tiles). BK=32, 8 k-steps. Per k-step per wave:
// 48 MFMA vs 32 ds_read_b64 -> MFMA-bound (~82% LDS headroom).
// dot = acc_hh + acc_x * 2^-11 ; then identical *_rn epilogue as the
// verified fp32 kernel (sqrt-key + u64 atomicMin).
__global__ __launch_bounds__(256, 2) void bmu_mfma_kernel(
    const _Float16* __restrict__ dh, const _Float16* __restrict__ dl,
    const _Float16* __restrict__ wh, const _Float16* __restrict__ wl,
    const float* __restrict__ wn2, const float* __restrict__ dn2,
    unsigned long long* __restrict__ bmu_best) {
  __shared__ char lds[32768];   // Ah | Al | Bh | Bl, each [128][64B]
  const int tid = threadIdx.x;
  const int lane = tid & 63;
  const int wid = tid >> 6;
  const int b0 = blockIdx.x * 128;
  const int n0 = blockIdx.y * 128;
  const int m0w = (wid >> 1) * 64;
  const int n0w = (wid & 1) * 64;
  const int lrow = lane & 15, lg = lane >> 4;

  f32x4 acch[4][4];
  f32x4 accx[4][4];
#pragma unroll
  for (int a = 0; a < 4; a++)
#pragma unroll
    for (int b = 0; b < 4; b++) { acch[a][b] = (f32x4)0.0f; accx[a][b] = (f32x4)0.0f; }

  // wave w stages array w:  0:Ah(data_hi) 1:Al 2:Bh(w_hi) 3:Bl
  const char* gbase =
      (wid == 0) ? (const char*)(dh + (size_t)b0 * FD) :
      (wid == 1) ? (const char*)(dl + (size_t)b0 * FD) :
      (wid == 2) ? (const char*)(wh + (size_t)n0 * FD) :
                   (const char*)(wl + (size_t)n0 * FD);
  char* lbase = (char*)lds + wid * 8192;

  const char* ldsAh = (const char*)lds;
  const char* ldsAl = (const char*)lds + 8192;
  const char* ldsBh = (const char*)lds + 16384;
  const char* ldsBl = (const char*)lds + 24576;

  for (int ks = 0; ks < 8; ks++) {
    __syncthreads();                      // previous step's reads complete
#pragma unroll
    for (int c = 0; c < 8; c++) {
      int row = c * 16 + (lane >> 2);
      int wb = ((lane & 3) * 16) ^ (((row >> 1) & 3) << 4);   // inverse-swizzled source
      const char* g = gbase + (size_t)row * 512 + ks * 64 + wb;
      GLOAD_LDS16(g, lbase + c * 1024);   // linear dest: base + lane*16
    }
    __syncthreads();                      // staging drained (compiler emits vmcnt)

    f16x8 ah[4], al[4];
#pragma unroll
    for (int mt = 0; mt < 4; mt++) {
      int r = m0w + mt * 16 + lrow;
      ah[mt] = readfrag(ldsAh, r, lg);
      al[mt] = readfrag(ldsAl, r, lg);
    }
#pragma unroll
    for (int nt = 0; nt < 4; nt++) {
      int r = n0w + nt * 16 + lrow;
      f16x8 bh = readfrag(ldsBh, r, lg);
      f16x8 bl = readfrag(ldsBl, r, lg);
#pragma unroll
      for (int mt = 0; mt < 4; mt++) {
        acch[mt][nt] = __builtin_amdgcn_mfma_f32_16x16x32_f16(ah[mt], bh, acch[mt][nt], 0, 0, 0);
        accx[mt][nt] = __builtin_amdgcn_mfma_f32_16x16x32_f16(ah[mt], bl, accx[mt][nt], 0, 0, 0);
        accx[mt][nt] = __builtin_amdgcn_mfma_f32_16x16x32_f16(al[mt], bh, accx[mt][nt], 0, 0, 0);
      }
    }
  }

  // Epilogue: D[mt][nt] lane mapping: sample_local = m0w+mt*16+lg*4+reg,
  // neuron_local = n0w+nt*16+lrow  (C/D layout HW-verified m89/m91).
#pragma unroll
  for (int mt = 0; mt < 4; mt++) {
    float d2s[4];
#pragma unroll
    for (int reg = 0; reg < 4; reg++)
      d2s[reg] = dn2[b0 + m0w + mt * 16 + lg * 4 + reg];
    unsigned long long bst[4] = {~0ull, ~0ull, ~0ull, ~0ull};
#pragma unroll
    for (int nt = 0; nt < 4; nt++) {
      int n = n0 + n0w + nt * 16 + lrow;
      float w2 = wn2[n];
#pragma unroll
      for (int reg = 0; reg < 4; reg++) {
        float dot = fmaf(accx[mt][nt][reg], 4.8828125e-4f, acch[mt][nt][reg]);  // hh + x/2048
        float t1 = __fadd_rn(d2s[reg], w2);
        float d2v = __fsub_rn(t1, __fmul_rn(2.0f, dot));
        float dist = sqrtf(fmaxf(d2v, 0.0f));
        unsigned long long p = ((unsigned long long)__float_as_uint(dist) << 32) | (unsigned)n;
        bst[reg] = (p < bst[reg]) ? p : bst[reg];
      }
    }
#pragma unroll
    for (int m = 8; m; m >>= 1)
#pragma unroll
      for (int reg = 0; reg < 4; reg++) {
        unsigned long long o = __shfl_xor(bst[reg], m);
        bst[reg] = (o < bst[reg]) ? o : bst[reg];
      }
    if (lrow == 0)
#pragma unroll
      for (int reg = 0; reg < 4; reg++)
        atomicMin(&bmu_best[b0 + m0w + mt * 16 + lg * 4 + reg], bst[reg]);
  }
}

// ---------------- K1-fallback (fp32 VALU, verified round 7) ----------------
__global__ __launch_bounds__(256) void bmu_kernel(const float* __restrict__ data,
                                                  const float* __restrict__ w,
                                                  const float* __restrict__ wn2,
                                                  const float* __restrict__ dn2,
                                                  unsigned long long* __restrict__ bmu_best) {
  __shared__ float As[128][36];
  __shared__ float Bs[32][132];
  const int tid = threadIdx.x;
  const int b0 = blockIdx.x * 128;
  const int n0 = blockIdx.y * 128;
  const int g = tid >> 4;
  const int c = tid & 15;

  float acc[8][8] = {};

  for (int f0 = 0; f0 < FD; f0 += 32) {
    __syncthreads();
#pragma unroll
    for (int i = 0; i < 4; i++) {
      int idx = i * 256 + tid;
      int r = idx >> 3, c4 = (idx & 7) * 4;
      float4 v = *reinterpret_cast<const float4*>(data + (size_t)(b0 + r) * FD + f0 + c4);
      *reinterpret_cast<float4*>(&As[r][c4]) = v;
    }
#pragma unroll
    for (int i = 0; i < 4; i++) {
      int idx = i * 256 + tid;
      int r = idx >> 3, c4 = (idx & 7) * 4;
      float4 v = *reinterpret_cast<const float4*>(w + (size_t)(n0 + r) * FD + f0 + c4);
      Bs[c4 + 0][r] = v.x; Bs[c4 + 1][r] = v.y; Bs[c4 + 2][r] = v.z; Bs[c4 + 3][r] = v.w;
    }
    __syncthreads();
#pragma unroll
    for (int k0 = 0; k0 < 32; k0 += 4) {
      float4 a4[8];
#pragma unroll
      for (int i = 0; i < 8; i++)
        a4[i] = *reinterpret_cast<const float4*>(&As[g + 16 * i][k0]);
#pragma unroll
      for (int kk = 0; kk < 4; kk++) {
        float4 bl = *reinterpret_cast<const float4*>(&Bs[k0 + kk][c * 4]);
        float4 bh = *reinterpret_cast<const float4*>(&Bs[k0 + kk][c * 4 + 64]);
#pragma unroll
        for (int i = 0; i < 8; i++) {
          float a = (kk == 0) ? a4[i].x : (kk == 1) ? a4[i].y : (kk == 2) ? a4[i].z : a4[i].w;
          acc[i][0] = fmaf(a, bl.x, acc[i][0]);
          acc[i][1] = fmaf(a, bl.y, acc[i][1]);
          acc[i][2] = fmaf(a, bl.z, acc[i][2]);
          acc[i][3] = fmaf(a, bl.w, acc[i][3]);
          acc[i][4] = fmaf(a, bh.x, acc[i][4]);
          acc[i][5] = fmaf(a, bh.y, acc[i][5]);
          acc[i][6] = fmaf(a, bh.z, acc[i][6]);
          acc[i][7] = fmaf(a, bh.w, acc[i][7]);
        }
      }
    }
  }
  float w2[8];
#pragma unroll
  for (int j = 0; j < 8; j++) {
    int nl = (j < 4) ? (c * 4 + j) : (64 + c * 4 + (j - 4));
    w2[j] = wn2[n0 + nl];
  }
  unsigned long long best[8];
#pragma unroll
  for (int i = 0; i < 8; i++) {
    float dn2s = dn2[b0 + g + 16 * i];
    best[i] = ~0ull;
#pragma unroll
    for (int j = 0; j < 8; j++) {
      int nl = (j < 4) ? (c * 4 + j) : (64 + c * 4 + (j - 4));
      float t1 = __fadd_rn(dn2s, w2[j]);
      float d2v = __fsub_rn(t1, __fmul_rn(2.0f, acc[i][j]));
      float dist = sqrtf(fmaxf(d2v, 0.0f));
      unsigned long long p = ((unsigned long long)__float_as_uint(dist) << 32) | (unsigned)(n0 + nl);
      best[i] = (p < best[i]) ? p : best[i];
    }
  }
#pragma unroll
  for (int m = 8; m; m >>= 1)
#pragma unroll
    for (int i = 0; i < 8; i++) {
      unsigned long long o = __shfl_xor(best[i], m);
      best[i] = (o < best[i]) ? o : best[i];
    }
  if (c == 0)
#pragma unroll
    for (int i = 0; i < 8; i++)
      atomicMin(&bmu_best[b0 + g + 16 * i], best[i]);
}

// ---------------- K3: truncated-window gather update (4x4 tiles, 1024 blocks) ----------------
__global__ __launch_bounds__(256) void update_kernel(const float* __restrict__ data,
                                                     const float* __restrict__ w,
                                                     const unsigned long long* __restrict__ bmu_best,
                                                     float* __restrict__ out) {
  __shared__ float axl[MAXS][4];
  __shared__ float ayl[MAXS][4];
  __shared__ int idxl[MAXS];
  __shared__ int cnt;
  __shared__ float red[16][17];
  __shared__ float nbsum_s[16];

  const int tid = threadIdx.x;
  const int tx0 = (blockIdx.x >> 5) * 4;   // 32 x-tiles
  const int ty0 = (blockIdx.x & 31) * 4;   // 32 y-tiles

  float acc[16] = {};
  float nbp = 0.f;
  const int myn = tid >> 4, q = tid & 15;
  const int mxi = myn >> 2, myi = myn & 3;

  for (int s0 = 0; s0 < BD; s0 += MAXS) {
    if (tid == 0) cnt = 0;
    __syncthreads();
#pragma unroll
    for (int i = 0; i < MAXS / 256; i++) {
      int s = s0 + i * 256 + tid;
      int bidx = (int)(bmu_best[s] & 0xFFFFFFFFull);
      int bx = bidx >> 7, by = bidx & 127;
      if (bx >= tx0 - RAD && bx <= tx0 + 3 + RAD &&
          by >= ty0 - RAD && by <= ty0 + 3 + RAD) {
        int pos = atomicAdd(&cnt, 1);
        idxl[pos] = s;
#pragma unroll
        for (int j = 0; j < 4; j++) {
          float dx = (float)(bx - (tx0 + j));
          float dy = (float)(by - (ty0 + j));
          axl[pos][j] = __expf(-dx * dx * 0.125f);
          ayl[pos][j] = __expf(-dy * dy * 0.125f);
        }
      }
    }
    __syncthreads();
    int cn = cnt;
    for (int s = 0; s < cn; s++) {
      float d = data[(size_t)idxl[s] * FD + tid];
#pragma unroll
      for (int xi = 0; xi < 4; xi++) {
        float t = axl[s][xi] * d;
#pragma unroll
        for (int yi = 0; yi < 4; yi++)
          acc[xi * 4 + yi] = fmaf(t, ayl[s][yi], acc[xi * 4 + yi]);
      }
    }
    for (int s = q; s < cn; s += 16) nbp += axl[s][mxi] * ayl[s][myi];
    __syncthreads();
  }

  red[myn][q] = nbp;
  __syncthreads();
  if (tid < 16) {
    float t = 0.f;
#pragma unroll
    for (int k = 0; k < 16; k++) t += red[tid][k];
    nbsum_s[tid] = t;
  }
  __syncthreads();

#pragma unroll
  for (int i = 0; i < 16; i++) {
    int n = (tx0 + (i >> 2)) * YD + (ty0 + (i & 3));
    size_t gi = (size_t)n * FD + tid;
    float wv = w[gi];
    out[gi] = fmaf(LRB, acc[i] - nbsum_s[i] * wv, wv);
  }
}

extern "C" void kernel_launch(void* const* d_in, const int* in_sizes, int n_in,
                              void* d_out, int out_size, void* d_ws, size_t ws_size,
                              hipStream_t stream) {
  const float* data = (const float*)d_in[0];
  const float* w = (const float*)d_in[1];
  float* out = (float*)d_out;

  char* ws = (char*)d_ws;
  float* wn2 = (float*)ws;                                           // 64 KB
  float* dn2 = (float*)(ws + 65536);                                 // 8 KB
  unsigned long long* bmu_best = (unsigned long long*)(ws + 73728);  // 16 KB
  _Float16* dh = (_Float16*)(ws + 90112);                            // 1 MB
  _Float16* dl = (_Float16*)(ws + 1138688);                          // 1 MB
  _Float16* wh = (_Float16*)(ws + 2187264);                          // 8 MB
  _Float16* wl = (_Float16*)(ws + 10575872);                         // 8 MB
  const size_t WS_NEED = 18964480;                                   // ~18.1 MB

  init_kernel<<<(BD + 255) / 256, 256, 0, stream>>>(bmu_best);
  rownorm2_kernel<<<ND / 4, 256, 0, stream>>>(w, wn2);
  rownorm2_kernel<<<BD / 4, 256, 0, stream>>>(data, dn2);

  if (ws_size >= WS_NEED) {
    split_kernel<<<(BD * FD / 4 + 255) / 256, 256, 0, stream>>>(data, dh, dl, BD * FD / 4);
    split_kernel<<<(ND * FD / 4 + 255) / 256, 256, 0, stream>>>(w, wh, wl, ND * FD / 4);
    bmu_mfma_kernel<<<dim3(BD / 128, ND / 128), 256, 0, stream>>>(dh, dl, wh, wl, wn2, dn2, bmu_best);
  } else {
    bmu_kernel<<<dim3(BD / 128, ND / 128), 256, 0, stream>>>(data, w, wn2, dn2, bmu_best);
  }

  update_kernel<<<XD / 4 * (YD / 4), 256, 0, stream>>>(data, w, bmu_best, out);
}

// Round 12
// 184.041 us; speedup vs baseline: 1.7788x; 1.0951x over previous
//
#include <hip/hip_runtime.h>
#include <hip/hip_fp16.h>

#define XD 128
#define YD 128
#define FD 256
#define BD 2048
#define ND (XD*YD)
#define LRB 2.44140625e-4f      // LR/B = 0.5/2048
#define RAD 14                  // exp(-(15^2)/8) ~ 6e-13: below fp32 output resolution
#define MAXS 512

typedef _Float16 f16x8 __attribute__((ext_vector_type(8)));
typedef _Float16 f16x4 __attribute__((ext_vector_type(4)));
typedef float    f32x4 __attribute__((ext_vector_type(4)));

#define GLOAD_LDS16(g, l) \
  __builtin_amdgcn_global_load_lds((const __attribute__((address_space(1))) void*)(g), \
                                   (__attribute__((address_space(3))) void*)(l), 16, 0, 0)

// 16B-block bank swizzle within each row's 64B k-block, keyed by row bits 1-2.
// With fragment-order layout this makes ds_read_b128 exactly 8 accesses/bank/wave.
__device__ __forceinline__ int swz(int row) { return ((row >> 1) & 3) << 4; }

// ---------------- K-prep (fused): init + rownorm + split-to-fragment-order ----------------
// Blocks [0, BD/4): data rows (4/block; blocks 0-7 also seed bmu_best).
// Blocks [BD/4, BD/4+ND/4): w rows.
// Per row (one wave): read 64 float4, norm via shfl, write 2-limb fp16 split in
// MFMA-fragment order (+bank swizzle): global byte layout per row (512B):
//   k32block*64 + slot ^ swz(row), slot = q<4 ? q*16 : (q-4)*16+8  (q = k4 % 8)
// so each lane's f16x8 MFMA operand (k = lg*4+j | 16+lg*4+j) is one linear 16B block.
__global__ __launch_bounds__(256) void prep_kernel(
    const float* __restrict__ data, const float* __restrict__ w,
    _Float16* __restrict__ dh, _Float16* __restrict__ dl,
    _Float16* __restrict__ wh, _Float16* __restrict__ wl,
    float* __restrict__ dn2, float* __restrict__ wn2,
    unsigned long long* __restrict__ bmu_best) {
  const int tid = threadIdx.x;
  const int bid = blockIdx.x;
  if (bid < 8) bmu_best[bid * 256 + tid] = ~0ull;

  const float* src; _Float16 *hi, *lo; float* nrm; int row;
  if (bid < BD / 4) { src = data; hi = dh; lo = dl; nrm = dn2; row = bid * 4 + (tid >> 6); }
  else { src = w; hi = wh; lo = wl; nrm = wn2; row = (bid - BD / 4) * 4 + (tid >> 6); }
  const int lane = tid & 63;

  float4 v = *reinterpret_cast<const float4*>(src + (size_t)row * FD + lane * 4);
  float s = v.x * v.x + v.y * v.y + v.z * v.z + v.w * v.w;
#pragma unroll
  for (int m = 32; m; m >>= 1) s += __shfl_xor(s, m);
  if (lane == 0) nrm[row] = s;

  f16x4 h, l;
  h[0] = (_Float16)v.x; l[0] = (_Float16)((v.x - (float)h[0]) * 2048.0f);
  h[1] = (_Float16)v.y; l[1] = (_Float16)((v.y - (float)h[1]) * 2048.0f);
  h[2] = (_Float16)v.z; l[2] = (_Float16)((v.z - (float)h[2]) * 2048.0f);
  h[3] = (_Float16)v.w; l[3] = (_Float16)((v.w - (float)h[3]) * 2048.0f);

  const int q = lane & 7, kb = lane >> 3;
  const int slot = (q < 4) ? (q * 16) : ((q - 4) * 16 + 8);
  const int off = kb * 64 + (slot ^ swz(row));
  *reinterpret_cast<f16x4*>((char*)hi + (size_t)row * 512 + off) = h;
  *reinterpret_cast<f16x4*>((char*)lo + (size_t)row * 512 + off) = l;
}

// One MFMA operand (16B) from fragment-ordered, swizzled LDS tile.
__device__ __forceinline__ f16x8 readfrag(const char* base, int r, int lg) {
  int off = (r * 64 + lg * 16) ^ swz(r);
  return *reinterpret_cast<const f16x8*>(base + off);
}

// Wave stages its 8KB array slice for k-step ks (linear: layout already permuted).
__device__ __forceinline__ void stage8(const char* gbase, char* lb, int ks, int lane) {
#pragma unroll
  for (int c = 0; c < 8; c++) {
    int row = c * 16 + (lane >> 2);
    const char* g = gbase + (size_t)row * 512 + (size_t)ks * 64 + (lane & 3) * 16;
    GLOAD_LDS16(g, lb + c * 1024);
  }
}

// ---------------- K1 (MFMA): split-fp16 BMU GEMM + argmin, double-buffered ----------------
// Block 128x128, 4 waves (64x64 quadrants, 4x4 of 16x16x32 tiles), BK=32, 8 k-steps.
// m97 pipeline: STAGE(ks+1) issued BEFORE frag-reads/MFMA of ks; one barrier per step
// (syncthreads' vmcnt/lgkm drain covers both the prefetch and the WAR on buf^1).
__global__ __launch_bounds__(256, 2) void bmu_mfma_kernel(
    const _Float16* __restrict__ dh, const _Float16* __restrict__ dl,
    const _Float16* __restrict__ wh, const _Float16* __restrict__ wl,
    const float* __restrict__ wn2, const float* __restrict__ dn2,
    unsigned long long* __restrict__ bmu_best) {
  __shared__ char lds[65536];   // [2 buf][Ah|Al|Bh|Bl][8KB]
  const int tid = threadIdx.x;
  const int lane = tid & 63;
  const int wid = tid >> 6;
  const int b0 = blockIdx.x * 128;
  const int n0 = blockIdx.y * 128;
  const int m0w = (wid >> 1) * 64;
  const int n0w = (wid & 1) * 64;
  const int lrow = lane & 15, lg = lane >> 4;

  f32x4 acch[4][4];
  f32x4 accx[4][4];
#pragma unroll
  for (int a = 0; a < 4; a++)
#pragma unroll
    for (int b = 0; b < 4; b++) { acch[a][b] = (f32x4)0.0f; accx[a][b] = (f32x4)0.0f; }

  // wave w stages array w: 0:Ah 1:Al 2:Bh 3:Bl
  const char* gbase =
      (wid == 0) ? (const char*)(dh + (size_t)b0 * FD) :
      (wid == 1) ? (const char*)(dl + (size_t)b0 * FD) :
      (wid == 2) ? (const char*)(wh + (size_t)n0 * FD) :
                   (const char*)(wl + (size_t)n0 * FD);

  stage8(gbase, (char*)lds + wid * 8192, 0, lane);
  __syncthreads();

  for (int ks = 0; ks < 8; ks++) {
    const int cur = ks & 1;
    if (ks < 7) stage8(gbase, (char*)lds + (cur ^ 1) * 32768 + wid * 8192, ks + 1, lane);

    const char* ldsAh = (const char*)lds + cur * 32768;
    const char* ldsAl = ldsAh + 8192;
    const char* ldsBh = ldsAh + 16384;
    const char* ldsBl = ldsAh + 24576;

    f16x8 ah[4], al[4];
#pragma unroll
    for (int mt = 0; mt < 4; mt++) {
      int r = m0w + mt * 16 + lrow;
      ah[mt] = readfrag(ldsAh, r, lg);
      al[mt] = readfrag(ldsAl, r, lg);
    }
#pragma unroll
    for (int nt = 0; nt < 4; nt++) {
      int r = n0w + nt * 16 + lrow;
      f16x8 bh = readfrag(ldsBh, r, lg);
      f16x8 bl = readfrag(ldsBl, r, lg);
#pragma unroll
      for (int mt = 0; mt < 4; mt++) {
        acch[mt][nt] = __builtin_amdgcn_mfma_f32_16x16x32_f16(ah[mt], bh, acch[mt][nt], 0, 0, 0);
        accx[mt][nt] = __builtin_amdgcn_mfma_f32_16x16x32_f16(ah[mt], bl, accx[mt][nt], 0, 0, 0);
        accx[mt][nt] = __builtin_amdgcn_mfma_f32_16x16x32_f16(al[mt], bh, accx[mt][nt], 0, 0, 0);
      }
    }
    __syncthreads();   // drains prefetch vmcnt + this step's lgkm; WAR-safe for buf^1
  }

  // Epilogue (HW-verified r8): sample = m0w+mt*16+lg*4+reg, neuron = n0w+nt*16+lrow.
#pragma unroll
  for (int mt = 0; mt < 4; mt++) {
    float d2s[4];
#pragma unroll
    for (int reg = 0; reg < 4; reg++)
      d2s[reg] = dn2[b0 + m0w + mt * 16 + lg * 4 + reg];
    unsigned long long bst[4] = {~0ull, ~0ull, ~0ull, ~0ull};
#pragma unroll
    for (int nt = 0; nt < 4; nt++) {
      int n = n0 + n0w + nt * 16 + lrow;
      float w2 = wn2[n];
#pragma unroll
      for (int reg = 0; reg < 4; reg++) {
        float dot = fmaf(accx[mt][nt][reg], 4.8828125e-4f, acch[mt][nt][reg]);  // hh + x/2048
        float t1 = __fadd_rn(d2s[reg], w2);
        float d2v = __fsub_rn(t1, __fmul_rn(2.0f, dot));
        float dist = sqrtf(fmaxf(d2v, 0.0f));
        unsigned long long p = ((unsigned long long)__float_as_uint(dist) << 32) | (unsigned)n;
        bst[reg] = (p < bst[reg]) ? p : bst[reg];
      }
    }
#pragma unroll
    for (int m = 8; m; m >>= 1)
#pragma unroll
      for (int reg = 0; reg < 4; reg++) {
        unsigned long long o = __shfl_xor(bst[reg], m);
        bst[reg] = (o < bst[reg]) ? o : bst[reg];
      }
    if (lrow == 0)
#pragma unroll
      for (int reg = 0; reg < 4; reg++)
        atomicMin(&bmu_best[b0 + m0w + mt * 16 + lg * 4 + reg], bst[reg]);
  }
}

// ---------------- fallback prep (only if ws too small) ----------------
__global__ __launch_bounds__(256) void init_kernel(unsigned long long* __restrict__ bmu_best) {
  int i = blockIdx.x * 256 + threadIdx.x;
  if (i < BD) bmu_best[i] = ~0ull;
}
__global__ __launch_bounds__(256) void rownorm2_kernel(const float* __restrict__ rows,
                                                       float* __restrict__ out) {
  int n = blockIdx.x * 4 + (threadIdx.x >> 6);
  int lane = threadIdx.x & 63;
  float4 v = *reinterpret_cast<const float4*>(rows + (size_t)n * FD + lane * 4);
  float s = v.x * v.x + v.y * v.y + v.z * v.z + v.w * v.w;
#pragma unroll
  for (int m = 32; m; m >>= 1) s += __shfl_xor(s, m);
  if (lane == 0) out[n] = s;
}

// ---------------- K1-fallback (fp32 VALU, verified round 7) ----------------
__global__ __launch_bounds__(256) void bmu_kernel(const float* __restrict__ data,
                                                  const float* __restrict__ w,
                                                  const float* __restrict__ wn2,
                                                  const float* __restrict__ dn2,
                                                  unsigned long long* __restrict__ bmu_best) {
  __shared__ float As[128][36];
  __shared__ float Bs[32][132];
  const int tid = threadIdx.x;
  const int b0 = blockIdx.x * 128;
  const int n0 = blockIdx.y * 128;
  const int g = tid >> 4;
  const int c = tid & 15;
  float acc[8][8] = {};
  for (int f0 = 0; f0 < FD; f0 += 32) {
    __syncthreads();
#pragma unroll
    for (int i = 0; i < 4; i++) {
      int idx = i * 256 + tid;
      int r = idx >> 3, c4 = (idx & 7) * 4;
      float4 v = *reinterpret_cast<const float4*>(data + (size_t)(b0 + r) * FD + f0 + c4);
      *reinterpret_cast<float4*>(&As[r][c4]) = v;
    }
#pragma unroll
    for (int i = 0; i < 4; i++) {
      int idx = i * 256 + tid;
      int r = idx >> 3, c4 = (idx & 7) * 4;
      float4 v = *reinterpret_cast<const float4*>(w + (size_t)(n0 + r) * FD + f0 + c4);
      Bs[c4 + 0][r] = v.x; Bs[c4 + 1][r] = v.y; Bs[c4 + 2][r] = v.z; Bs[c4 + 3][r] = v.w;
    }
    __syncthreads();
#pragma unroll
    for (int k0 = 0; k0 < 32; k0 += 4) {
      float4 a4[8];
#pragma unroll
      for (int i = 0; i < 8; i++)
        a4[i] = *reinterpret_cast<const float4*>(&As[g + 16 * i][k0]);
#pragma unroll
      for (int kk = 0; kk < 4; kk++) {
        float4 bl = *reinterpret_cast<const float4*>(&Bs[k0 + kk][c * 4]);
        float4 bh = *reinterpret_cast<const float4*>(&Bs[k0 + kk][c * 4 + 64]);
#pragma unroll
        for (int i = 0; i < 8; i++) {
          float a = (kk == 0) ? a4[i].x : (kk == 1) ? a4[i].y : (kk == 2) ? a4[i].z : a4[i].w;
          acc[i][0] = fmaf(a, bl.x, acc[i][0]);
          acc[i][1] = fmaf(a, bl.y, acc[i][1]);
          acc[i][2] = fmaf(a, bl.z, acc[i][2]);
          acc[i][3] = fmaf(a, bl.w, acc[i][3]);
          acc[i][4] = fmaf(a, bh.x, acc[i][4]);
          acc[i][5] = fmaf(a, bh.y, acc[i][5]);
          acc[i][6] = fmaf(a, bh.z, acc[i][6]);
          acc[i][7] = fmaf(a, bh.w, acc[i][7]);
        }
      }
    }
  }
  float w2[8];
#pragma unroll
  for (int j = 0; j < 8; j++) {
    int nl = (j < 4) ? (c * 4 + j) : (64 + c * 4 + (j - 4));
    w2[j] = wn2[n0 + nl];
  }
  unsigned long long best[8];
#pragma unroll
  for (int i = 0; i < 8; i++) {
    float dn2s = dn2[b0 + g + 16 * i];
    best[i] = ~0ull;
#pragma unroll
    for (int j = 0; j < 8; j++) {
      int nl = (j < 4) ? (c * 4 + j) : (64 + c * 4 + (j - 4));
      float t1 = __fadd_rn(dn2s, w2[j]);
      float d2v = __fsub_rn(t1, __fmul_rn(2.0f, acc[i][j]));
      float dist = sqrtf(fmaxf(d2v, 0.0f));
      unsigned long long p = ((unsigned long long)__float_as_uint(dist) << 32) | (unsigned)(n0 + nl);
      best[i] = (p < best[i]) ? p : best[i];
    }
  }
#pragma unroll
  for (int m = 8; m; m >>= 1)
#pragma unroll
    for (int i = 0; i < 8; i++) {
      unsigned long long o = __shfl_xor(best[i], m);
      best[i] = (o < best[i]) ? o : best[i];
    }
  if (c == 0)
#pragma unroll
    for (int i = 0; i < 8; i++)
      atomicMin(&bmu_best[b0 + g + 16 * i], best[i]);
}

// ---------------- K3: truncated-window gather update (4x4 tiles, 1024 blocks) ----------------
__global__ __launch_bounds__(256) void update_kernel(const float* __restrict__ data,
                                                     const float* __restrict__ w,
                                                     const unsigned long long* __restrict__ bmu_best,
                                                     float* __restrict__ out) {
  __shared__ float axl[MAXS][4];
  __shared__ float ayl[MAXS][4];
  __shared__ int idxl[MAXS];
  __shared__ int cnt;
  __shared__ float red[16][17];
  __shared__ float nbsum_s[16];

  const int tid = threadIdx.x;
  const int tx0 = (blockIdx.x >> 5) * 4;
  const int ty0 = (blockIdx.x & 31) * 4;

  float acc[16] = {};
  float nbp = 0.f;
  const int myn = tid >> 4, q = tid & 15;
  const int mxi = myn >> 2, myi = myn & 3;

  for (int s0 = 0; s0 < BD; s0 += MAXS) {
    if (tid == 0) cnt = 0;
    __syncthreads();
#pragma unroll
    for (int i = 0; i < MAXS / 256; i++) {
      int s = s0 + i * 256 + tid;
      int bidx = (int)(bmu_best[s] & 0xFFFFFFFFull);
      int bx = bidx >> 7, by = bidx & 127;
      if (bx >= tx0 - RAD && bx <= tx0 + 3 + RAD &&
          by >= ty0 - RAD && by <= ty0 + 3 + RAD) {
        int pos = atomicAdd(&cnt, 1);
        idxl[pos] = s;
#pragma unroll
        for (int j = 0; j < 4; j++) {
          float dx = (float)(bx - (tx0 + j));
          float dy = (float)(by - (ty0 + j));
          axl[pos][j] = __expf(-dx * dx * 0.125f);
          ayl[pos][j] = __expf(-dy * dy * 0.125f);
        }
      }
    }
    __syncthreads();
    int cn = cnt;
    for (int s = 0; s < cn; s++) {
      float d = data[(size_t)idxl[s] * FD + tid];
#pragma unroll
      for (int xi = 0; xi < 4; xi++) {
        float t = axl[s][xi] * d;
#pragma unroll
        for (int yi = 0; yi < 4; yi++)
          acc[xi * 4 + yi] = fmaf(t, ayl[s][yi], acc[xi * 4 + yi]);
      }
    }
    for (int s = q; s < cn; s += 16) nbp += axl[s][mxi] * ayl[s][myi];
    __syncthreads();
  }

  red[myn][q] = nbp;
  __syncthreads();
  if (tid < 16) {
    float t = 0.f;
#pragma unroll
    for (int k = 0; k < 16; k++) t += red[tid][k];
    nbsum_s[tid] = t;
  }
  __syncthreads();

#pragma unroll
  for (int i = 0; i < 16; i++) {
    int n = (tx0 + (i >> 2)) * YD + (ty0 + (i & 3));
    size_t gi = (size_t)n * FD + tid;
    float wv = w[gi];
    out[gi] = fmaf(LRB, acc[i] - nbsum_s[i] * wv, wv);
  }
}

extern "C" void kernel_launch(void* const* d_in, const int* in_sizes, int n_in,
                              void* d_out, int out_size, void* d_ws, size_t ws_size,
                              hipStream_t stream) {
  const float* data = (const float*)d_in[0];
  const float* w = (const float*)d_in[1];
  float* out = (float*)d_out;

  char* ws = (char*)d_ws;
  float* wn2 = (float*)ws;                                           // 64 KB
  float* dn2 = (float*)(ws + 65536);                                 // 8 KB
  unsigned long long* bmu_best = (unsigned long long*)(ws + 73728);  // 16 KB
  _Float16* dh = (_Float16*)(ws + 90112);                            // 1 MB
  _Float16* dl = (_Float16*)(ws + 1138688);                          // 1 MB
  _Float16* wh = (_Float16*)(ws + 2187264);                          // 8 MB
  _Float16* wl = (_Float16*)(ws + 10575872);                         // 8 MB
  const size_t WS_NEED = 18964480;

  if (ws_size >= WS_NEED) {
    prep_kernel<<<BD / 4 + ND / 4, 256, 0, stream>>>(data, w, dh, dl, wh, wl, dn2, wn2, bmu_best);
    bmu_mfma_kernel<<<dim3(BD / 128, ND / 128), 256, 0, stream>>>(dh, dl, wh, wl, wn2, dn2, bmu_best);
  } else {
    init_kernel<<<(BD + 255) / 256, 256, 0, stream>>>(bmu_best);
    rownorm2_kernel<<<ND / 4, 256, 0, stream>>>(w, wn2);
    rownorm2_kernel<<<BD / 4, 256, 0, stream>>>(data, dn2);
    bmu_kernel<<<dim3(BD / 128, ND / 128), 256, 0, stream>>>(data, w, wn2, dn2, bmu_best);
  }

  update_kernel<<<XD / 4 * (YD / 4), 256, 0, stream>>>(data, w, bmu_best, out);
}

// Round 13
// 174.900 us; speedup vs baseline: 1.8718x; 1.0523x over previous
//
#include <hip/hip_runtime.h>
#include <hip/hip_fp16.h>

#define XD 128
#define YD 128
#define FD 256
#define BD 2048
#define ND (XD*YD)
#define LRB 2.44140625e-4f      // LR/B = 0.5/2048
#define RAD 14                  // exp(-(15^2)/8) ~ 6e-13: below fp32 output resolution
#define MAXS 512

typedef _Float16 f16x8 __attribute__((ext_vector_type(8)));
typedef _Float16 f16x4 __attribute__((ext_vector_type(4)));
typedef float    f32x4 __attribute__((ext_vector_type(4)));

#define GLOAD_LDS16(g, l) \
  __builtin_amdgcn_global_load_lds((const __attribute__((address_space(1))) void*)(g), \
                                   (__attribute__((address_space(3))) void*)(l), 16, 0, 0)

// 16B-block bank swizzle within each row's 64B k-block, keyed by row bits 1-2.
// With fragment-order layout this makes ds_read_b128 exactly 8 accesses/bank/wave.
// (HW-verified r12: SQ_LDS_BANK_CONFLICT == 0.)
__device__ __forceinline__ int swz(int row) { return ((row >> 1) & 3) << 4; }

// ---------------- K-prep (fused): init + rownorm + split-to-fragment-order ----------------
__global__ __launch_bounds__(256) void prep_kernel(
    const float* __restrict__ data, const float* __restrict__ w,
    _Float16* __restrict__ dh, _Float16* __restrict__ dl,
    _Float16* __restrict__ wh, _Float16* __restrict__ wl,
    float* __restrict__ dn2, float* __restrict__ wn2,
    unsigned long long* __restrict__ bmu_best) {
  const int tid = threadIdx.x;
  const int bid = blockIdx.x;
  if (bid < 8) bmu_best[bid * 256 + tid] = ~0ull;

  const float* src; _Float16 *hi, *lo; float* nrm; int row;
  if (bid < BD / 4) { src = data; hi = dh; lo = dl; nrm = dn2; row = bid * 4 + (tid >> 6); }
  else { src = w; hi = wh; lo = wl; nrm = wn2; row = (bid - BD / 4) * 4 + (tid >> 6); }
  const int lane = tid & 63;

  float4 v = *reinterpret_cast<const float4*>(src + (size_t)row * FD + lane * 4);
  float s = v.x * v.x + v.y * v.y + v.z * v.z + v.w * v.w;
#pragma unroll
  for (int m = 32; m; m >>= 1) s += __shfl_xor(s, m);
  if (lane == 0) nrm[row] = s;

  f16x4 h, l;
  h[0] = (_Float16)v.x; l[0] = (_Float16)((v.x - (float)h[0]) * 2048.0f);
  h[1] = (_Float16)v.y; l[1] = (_Float16)((v.y - (float)h[1]) * 2048.0f);
  h[2] = (_Float16)v.z; l[2] = (_Float16)((v.z - (float)h[2]) * 2048.0f);
  h[3] = (_Float16)v.w; l[3] = (_Float16)((v.w - (float)h[3]) * 2048.0f);

  const int q = lane & 7, kb = lane >> 3;
  const int slot = (q < 4) ? (q * 16) : ((q - 4) * 16 + 8);
  const int off = kb * 64 + (slot ^ swz(row));
  *reinterpret_cast<f16x4*>((char*)hi + (size_t)row * 512 + off) = h;
  *reinterpret_cast<f16x4*>((char*)lo + (size_t)row * 512 + off) = l;
}

// One MFMA operand (16B) from fragment-ordered, swizzled LDS tile.
__device__ __forceinline__ f16x8 readfrag(const char* base, int r, int lg) {
  int off = (r * 64 + lg * 16) ^ swz(r);
  return *reinterpret_cast<const f16x8*>(base + off);
}

// Wave stages its 8KB array slice for k-step ks (linear: layout already permuted).
__device__ __forceinline__ void stage8(const char* gbase, char* lb, int ks, int lane) {
#pragma unroll
  for (int c = 0; c < 8; c++) {
    int row = c * 16 + (lane >> 2);
    const char* g = gbase + (size_t)row * 512 + (size_t)ks * 64 + (lane & 3) * 16;
    GLOAD_LDS16(g, lb + c * 1024);
  }
}

// ---------------- K1 (MFMA): split-fp16 BMU GEMM + argmin, double-buffered ----------------
// Block 128x128, 4 waves (64x64 quadrants, 4x4 of 16x16x32 tiles), BK=32, 8 k-steps.
// r13: bijective XCD swizzle (T1) — XCD k owns 16 consecutive y-rows, so its
// working set (16 B-panels = 2 MB + A 2 MB) fits the 4 MB per-XCD L2 and the
// staging loads become L2 hits the 1-ahead prefetch can fully hide.
__global__ __launch_bounds__(256, 2) void bmu_mfma_kernel(
    const _Float16* __restrict__ dh, const _Float16* __restrict__ dl,
    const _Float16* __restrict__ wh, const _Float16* __restrict__ wl,
    const float* __restrict__ wn2, const float* __restrict__ dn2,
    unsigned long long* __restrict__ bmu_best) {
  __shared__ char lds[65536];   // [2 buf][Ah|Al|Bh|Bl][8KB]
  const int tid = threadIdx.x;
  const int lane = tid & 63;
  const int wid = tid >> 6;

  // XCD swizzle: hw linear id (x-fastest) -> logical, chunked per XCD.
  // 2048 blocks % 8 XCDs == 0 -> bijection (lin&7)*256 + lin>>3.
  const int lin = blockIdx.x + blockIdx.y * 16;   // gridDim.x == 16
  const int lp  = (lin & 7) * 256 + (lin >> 3);
  const int b0 = (lp & 15) * 128;
  const int n0 = (lp >> 4) * 128;

  const int m0w = (wid >> 1) * 64;
  const int n0w = (wid & 1) * 64;
  const int lrow = lane & 15, lg = lane >> 4;

  f32x4 acch[4][4];
  f32x4 accx[4][4];
#pragma unroll
  for (int a = 0; a < 4; a++)
#pragma unroll
    for (int b = 0; b < 4; b++) { acch[a][b] = (f32x4)0.0f; accx[a][b] = (f32x4)0.0f; }

  // wave w stages array w: 0:Ah 1:Al 2:Bh 3:Bl
  const char* gbase =
      (wid == 0) ? (const char*)(dh + (size_t)b0 * FD) :
      (wid == 1) ? (const char*)(dl + (size_t)b0 * FD) :
      (wid == 2) ? (const char*)(wh + (size_t)n0 * FD) :
                   (const char*)(wl + (size_t)n0 * FD);

  stage8(gbase, (char*)lds + wid * 8192, 0, lane);
  __syncthreads();

  for (int ks = 0; ks < 8; ks++) {
    const int cur = ks & 1;
    if (ks < 7) stage8(gbase, (char*)lds + (cur ^ 1) * 32768 + wid * 8192, ks + 1, lane);

    const char* ldsAh = (const char*)lds + cur * 32768;
    const char* ldsAl = ldsAh + 8192;
    const char* ldsBh = ldsAh + 16384;
    const char* ldsBl = ldsAh + 24576;

    f16x8 ah[4], al[4];
#pragma unroll
    for (int mt = 0; mt < 4; mt++) {
      int r = m0w + mt * 16 + lrow;
      ah[mt] = readfrag(ldsAh, r, lg);
      al[mt] = readfrag(ldsAl, r, lg);
    }
#pragma unroll
    for (int nt = 0; nt < 4; nt++) {
      int r = n0w + nt * 16 + lrow;
      f16x8 bh = readfrag(ldsBh, r, lg);
      f16x8 bl = readfrag(ldsBl, r, lg);
#pragma unroll
      for (int mt = 0; mt < 4; mt++) {
        acch[mt][nt] = __builtin_amdgcn_mfma_f32_16x16x32_f16(ah[mt], bh, acch[mt][nt], 0, 0, 0);
        accx[mt][nt] = __builtin_amdgcn_mfma_f32_16x16x32_f16(ah[mt], bl, accx[mt][nt], 0, 0, 0);
        accx[mt][nt] = __builtin_amdgcn_mfma_f32_16x16x32_f16(al[mt], bh, accx[mt][nt], 0, 0, 0);
      }
    }
    __syncthreads();   // drains prefetch vmcnt + this step's lgkm; WAR-safe for buf^1
  }

  // Epilogue (HW-verified r8): sample = m0w+mt*16+lg*4+reg, neuron = n0w+nt*16+lrow.
#pragma unroll
  for (int mt = 0; mt < 4; mt++) {
    float d2s[4];
#pragma unroll
    for (int reg = 0; reg < 4; reg++)
      d2s[reg] = dn2[b0 + m0w + mt * 16 + lg * 4 + reg];
    unsigned long long bst[4] = {~0ull, ~0ull, ~0ull, ~0ull};
#pragma unroll
    for (int nt = 0; nt < 4; nt++) {
      int n = n0 + n0w + nt * 16 + lrow;
      float w2 = wn2[n];
#pragma unroll
      for (int reg = 0; reg < 4; reg++) {
        float dot = fmaf(accx[mt][nt][reg], 4.8828125e-4f, acch[mt][nt][reg]);  // hh + x/2048
        float t1 = __fadd_rn(d2s[reg], w2);
        float d2v = __fsub_rn(t1, __fmul_rn(2.0f, dot));
        float dist = sqrtf(fmaxf(d2v, 0.0f));
        unsigned long long p = ((unsigned long long)__float_as_uint(dist) << 32) | (unsigned)n;
        bst[reg] = (p < bst[reg]) ? p : bst[reg];
      }
    }
#pragma unroll
    for (int m = 8; m; m >>= 1)
#pragma unroll
      for (int reg = 0; reg < 4; reg++) {
        unsigned long long o = __shfl_xor(bst[reg], m);
        bst[reg] = (o < bst[reg]) ? o : bst[reg];
      }
    if (lrow == 0)
#pragma unroll
      for (int reg = 0; reg < 4; reg++)
        atomicMin(&bmu_best[b0 + m0w + mt * 16 + lg * 4 + reg], bst[reg]);
  }
}

// ---------------- fallback prep (only if ws too small) ----------------
__global__ __launch_bounds__(256) void init_kernel(unsigned long long* __restrict__ bmu_best) {
  int i = blockIdx.x * 256 + threadIdx.x;
  if (i < BD) bmu_best[i] = ~0ull;
}
__global__ __launch_bounds__(256) void rownorm2_kernel(const float* __restrict__ rows,
                                                       float* __restrict__ out) {
  int n = blockIdx.x * 4 + (threadIdx.x >> 6);
  int lane = threadIdx.x & 63;
  float4 v = *reinterpret_cast<const float4*>(rows + (size_t)n * FD + lane * 4);
  float s = v.x * v.x + v.y * v.y + v.z * v.z + v.w * v.w;
#pragma unroll
  for (int m = 32; m; m >>= 1) s += __shfl_xor(s, m);
  if (lane == 0) out[n] = s;
}

// ---------------- K1-fallback (fp32 VALU, verified round 7) ----------------
__global__ __launch_bounds__(256) void bmu_kernel(const float* __restrict__ data,
                                                  const float* __restrict__ w,
                                                  const float* __restrict__ wn2,
                                                  const float* __restrict__ dn2,
                                                  unsigned long long* __restrict__ bmu_best) {
  __shared__ float As[128][36];
  __shared__ float Bs[32][132];
  const int tid = threadIdx.x;
  const int b0 = blockIdx.x * 128;
  const int n0 = blockIdx.y * 128;
  const int g = tid >> 4;
  const int c = tid & 15;
  float acc[8][8] = {};
  for (int f0 = 0; f0 < FD; f0 += 32) {
    __syncthreads();
#pragma unroll
    for (int i = 0; i < 4; i++) {
      int idx = i * 256 + tid;
      int r = idx >> 3, c4 = (idx & 7) * 4;
      float4 v = *reinterpret_cast<const float4*>(data + (size_t)(b0 + r) * FD + f0 + c4);
      *reinterpret_cast<float4*>(&As[r][c4]) = v;
    }
#pragma unroll
    for (int i = 0; i < 4; i++) {
      int idx = i * 256 + tid;
      int r = idx >> 3, c4 = (idx & 7) * 4;
      float4 v = *reinterpret_cast<const float4*>(w + (size_t)(n0 + r) * FD + f0 + c4);
      Bs[c4 + 0][r] = v.x; Bs[c4 + 1][r] = v.y; Bs[c4 + 2][r] = v.z; Bs[c4 + 3][r] = v.w;
    }
    __syncthreads();
#pragma unroll
    for (int k0 = 0; k0 < 32; k0 += 4) {
      float4 a4[8];
#pragma unroll
      for (int i = 0; i < 8; i++)
        a4[i] = *reinterpret_cast<const float4*>(&As[g + 16 * i][k0]);
#pragma unroll
      for (int kk = 0; kk < 4; kk++) {
        float4 bl = *reinterpret_cast<const float4*>(&Bs[k0 + kk][c * 4]);
        float4 bh = *reinterpret_cast<const float4*>(&Bs[k0 + kk][c * 4 + 64]);
#pragma unroll
        for (int i = 0; i < 8; i++) {
          float a = (kk == 0) ? a4[i].x : (kk == 1) ? a4[i].y : (kk == 2) ? a4[i].z : a4[i].w;
          acc[i][0] = fmaf(a, bl.x, acc[i][0]);
          acc[i][1] = fmaf(a, bl.y, acc[i][1]);
          acc[i][2] = fmaf(a, bl.z, acc[i][2]);
          acc[i][3] = fmaf(a, bl.w, acc[i][3]);
          acc[i][4] = fmaf(a, bh.x, acc[i][4]);
          acc[i][5] = fmaf(a, bh.y, acc[i][5]);
          acc[i][6] = fmaf(a, bh.z, acc[i][6]);
          acc[i][7] = fmaf(a, bh.w, acc[i][7]);
        }
      }
    }
  }
  float w2[8];
#pragma unroll
  for (int j = 0; j < 8; j++) {
    int nl = (j < 4) ? (c * 4 + j) : (64 + c * 4 + (j - 4));
    w2[j] = wn2[n0 + nl];
  }
  unsigned long long best[8];
#pragma unroll
  for (int i = 0; i < 8; i++) {
    float dn2s = dn2[b0 + g + 16 * i];
    best[i] = ~0ull;
#pragma unroll
    for (int j = 0; j < 8; j++) {
      int nl = (j < 4) ? (c * 4 + j) : (64 + c * 4 + (j - 4));
      float t1 = __fadd_rn(dn2s, w2[j]);
      float d2v = __fsub_rn(t1, __fmul_rn(2.0f, acc[i][j]));
      float dist = sqrtf(fmaxf(d2v, 0.0f));
      unsigned long long p = ((unsigned long long)__float_as_uint(dist) << 32) | (unsigned)(n0 + nl);
      best[i] = (p < best[i]) ? p : best[i];
    }
  }
#pragma unroll
  for (int m = 8; m; m >>= 1)
#pragma unroll
    for (int i = 0; i < 8; i++) {
      unsigned long long o = __shfl_xor(best[i], m);
      best[i] = (o < best[i]) ? o : best[i];
    }
  if (c == 0)
#pragma unroll
    for (int i = 0; i < 8; i++)
      atomicMin(&bmu_best[b0 + g + 16 * i], best[i]);
}

// ---------------- K3: truncated-window gather update (4x4 tiles, 1024 blocks) ----------------
__global__ __launch_bounds__(256) void update_kernel(const float* __restrict__ data,
                                                     const float* __restrict__ w,
                                                     const unsigned long long* __restrict__ bmu_best,
                                                     float* __restrict__ out) {
  __shared__ float axl[MAXS][4];
  __shared__ float ayl[MAXS][4];
  __shared__ int idxl[MAXS];
  __shared__ int cnt;
  __shared__ float red[16][17];
  __shared__ float nbsum_s[16];

  const int tid = threadIdx.x;
  const int tx0 = (blockIdx.x >> 5) * 4;
  const int ty0 = (blockIdx.x & 31) * 4;

  float acc[16] = {};
  float nbp = 0.f;
  const int myn = tid >> 4, q = tid & 15;
  const int mxi = myn >> 2, myi = myn & 3;

  for (int s0 = 0; s0 < BD; s0 += MAXS) {
    if (tid == 0) cnt = 0;
    __syncthreads();
#pragma unroll
    for (int i = 0; i < MAXS / 256; i++) {
      int s = s0 + i * 256 + tid;
      int bidx = (int)(bmu_best[s] & 0xFFFFFFFFull);
      int bx = bidx >> 7, by = bidx & 127;
      if (bx >= tx0 - RAD && bx <= tx0 + 3 + RAD &&
          by >= ty0 - RAD && by <= ty0 + 3 + RAD) {
        int pos = atomicAdd(&cnt, 1);
        idxl[pos] = s;
#pragma unroll
        for (int j = 0; j < 4; j++) {
          float dx = (float)(bx - (tx0 + j));
          float dy = (float)(by - (ty0 + j));
          axl[pos][j] = __expf(-dx * dx * 0.125f);
          ayl[pos][j] = __expf(-dy * dy * 0.125f);
        }
      }
    }
    __syncthreads();
    int cn = cnt;
    for (int s = 0; s < cn; s++) {
      float d = data[(size_t)idxl[s] * FD + tid];
#pragma unroll
      for (int xi = 0; xi < 4; xi++) {
        float t = axl[s][xi] * d;
#pragma unroll
        for (int yi = 0; yi < 4; yi++)
          acc[xi * 4 + yi] = fmaf(t, ayl[s][yi], acc[xi * 4 + yi]);
      }
    }
    for (int s = q; s < cn; s += 16) nbp += axl[s][mxi] * ayl[s][myi];
    __syncthreads();
  }

  red[myn][q] = nbp;
  __syncthreads();
  if (tid < 16) {
    float t = 0.f;
#pragma unroll
    for (int k = 0; k < 16; k++) t += red[tid][k];
    nbsum_s[tid] = t;
  }
  __syncthreads();

#pragma unroll
  for (int i = 0; i < 16; i++) {
    int n = (tx0 + (i >> 2)) * YD + (ty0 + (i & 3));
    size_t gi = (size_t)n * FD + tid;
    float wv = w[gi];
    out[gi] = fmaf(LRB, acc[i] - nbsum_s[i] * wv, wv);
  }
}

extern "C" void kernel_launch(void* const* d_in, const int* in_sizes, int n_in,
                              void* d_out, int out_size, void* d_ws, size_t ws_size,
                              hipStream_t stream) {
  const float* data = (const float*)d_in[0];
  const float* w = (const float*)d_in[1];
  float* out = (float*)d_out;

  char* ws = (char*)d_ws;
  float* wn2 = (float*)ws;                                           // 64 KB
  float* dn2 = (float*)(ws + 65536);                                 // 8 KB
  unsigned long long* bmu_best = (unsigned long long*)(ws + 73728);  // 16 KB
  _Float16* dh = (_Float16*)(ws + 90112);                            // 1 MB
  _Float16* dl = (_Float16*)(ws + 1138688);                          // 1 MB
  _Float16* wh = (_Float16*)(ws + 2187264);                          // 8 MB
  _Float16* wl = (_Float16*)(ws + 10575872);                         // 8 MB
  const size_t WS_NEED = 18964480;

  if (ws_size >= WS_NEED) {
    prep_kernel<<<BD / 4 + ND / 4, 256, 0, stream>>>(data, w, dh, dl, wh, wl, dn2, wn2, bmu_best);
    bmu_mfma_kernel<<<dim3(BD / 128, ND / 128), 256, 0, stream>>>(dh, dl, wh, wl, wn2, dn2, bmu_best);
  } else {
    init_kernel<<<(BD + 255) / 256, 256, 0, stream>>>(bmu_best);
    rownorm2_kernel<<<ND / 4, 256, 0, stream>>>(w, wn2);
    rownorm2_kernel<<<BD / 4, 256, 0, stream>>>(data, dn2);
    bmu_kernel<<<dim3(BD / 128, ND / 128), 256, 0, stream>>>(data, w, wn2, dn2, bmu_best);
  }

  update_kernel<<<XD / 4 * (YD / 4), 256, 0, stream>>>(data, w, bmu_best, out);
}